// Round 15
// baseline (21465.048 us; speedup 1.0000x reference)
//
#include <hip/hip_runtime.h>
#include <cstdint>

// Reference semantics (validated, absmax=0.0 — DO NOT change arithmetic):
//  - selection on RAW f32 coords, distance = fma(dz,dz, fma(dx,dx, dy*dy))
//    with dx/dy/dz plain f32 subs;
//  - min/argmax exact, FIRST-index tie-break (min global point index);
//  - output coords bf16-RNE-rounded, batch = float b.
//
// R26: R19's internals are exhausted (VALU cut, DS cut, tail cut, occupancy,
// packing all regressed; VALUBusy ~100% on the 16 active CUs). Remaining
// lever: 240 idle CUs. R14's 8-way split died at ~19us/iter sync because the
// POLL used ACQUIRE loads -> per-poll cache-invalidate storm from 128 waves.
// This round: 2 blocks/cloud (32 blocks; bid=r*16+b keeps both on XCD b%8),
// R19 structure per block (8 slots), and a minimal handshake:
//   writer(t==0): relaxed key store, RELEASE tag store      (once/iter)
//   readers(all waves): RELAXED (glc, no invalidate) tag poll ==j,
//                       ONE acquire fence, relaxed key load (once/iter)
// Same parity-doubled slots + exact-tag protocol as R14 (proven correct).
// Winner may be remote -> center = 3 uniform scalar loads from xb (L2).
// LDS padded to 88.25KB -> 1 block/CU.
#pragma clang fp contract(off)

#define B_ 16
#define N_ 16384
#define K_ 4096
#define G_ 2                    // blocks per cloud
#define THREADS_ 1024
#define PPB_ (N_ / G_)          // 8192 points per block
#define NW_ (THREADS_ / 64)     // 16 waves per block
#define XYPAD_ 11264            // float2 slots (88KB) -> forces 1 block/CU

#define PTS_LIST(X) X(0) X(1) X(2) X(3) X(4) X(5) X(6) X(7)

// f32 -> bf16 RNE, returned as the bf16-representable f32 (finite inputs)
__device__ __forceinline__ float bfr(float f) {
  union { float f; uint32_t i; } c; c.f = f;
  c.i = (c.i + 0x7FFFu + ((c.i >> 16) & 1u)) & 0xFFFF0000u;
  return c.f;
}

// ---- DPP helpers (ctrl is a template constant) -----------------------------
template <int CTRL>
__device__ __forceinline__ float dpp_fmax(float v) {
  union { float f; int i; } s, p;
  s.f = v;
  p.i = __builtin_amdgcn_update_dpp(0, s.i, CTRL, 0xF, 0xF, false);
  return fmaxf(v, p.f);
}
template <int CTRL>
__device__ __forceinline__ unsigned dpp_umin(unsigned v) {
  const int p = __builtin_amdgcn_update_dpp((int)0xFFFFFFFFu, (int)v,
                                            CTRL, 0xF, 0xF, false);
  const unsigned pu = (unsigned)p;
  return pu < v ? pu : v;
}

// wave-wide (max bv, min bg among maxed) -> (wv, wg), uniform in all lanes.
__device__ __forceinline__ void wave_argmax(float bv, unsigned bg,
                                            float& wv, unsigned& wg) {
  float v = bv;
  v = dpp_fmax<0x111>(v);  // row_shr:1
  v = dpp_fmax<0x112>(v);  // row_shr:2
  v = dpp_fmax<0x114>(v);  // row_shr:4
  v = dpp_fmax<0x118>(v);  // row_shr:8
  v = dpp_fmax<0x142>(v);  // row_bcast:15
  v = dpp_fmax<0x143>(v);  // row_bcast:31
  union { float f; int i; } mx;
  mx.i = __builtin_amdgcn_readlane(__builtin_bit_cast(int, v), 63);
  unsigned c = (bv == mx.f) ? bg : 0xFFFFFFFFu;
  c = dpp_umin<0x111>(c);
  c = dpp_umin<0x112>(c);
  c = dpp_umin<0x114>(c);
  c = dpp_umin<0x118>(c);
  c = dpp_umin<0x142>(c);
  c = dpp_umin<0x143>(c);
  wg = (unsigned)__builtin_amdgcn_readlane((int)c, 63);
  wv = mx.f;
}

// u64 key max over a DPP lane-permutation (block-finalize butterfly; key is
// (f32bits(dist)<<32)|~idx so u64 max == (max dist, min index)). Exact.
template <int CTRL>
__device__ __forceinline__ unsigned long long kmax_dpp(unsigned long long k) {
  const int lo = (int)(unsigned)k;
  const int hi = (int)(unsigned)(k >> 32);
  const int plo = __builtin_amdgcn_update_dpp(lo, lo, CTRL, 0xF, 0xF, true);
  const int phi = __builtin_amdgcn_update_dpp(hi, hi, CTRL, 0xF, 0xF, true);
  const unsigned long long ok =
      ((unsigned long long)(unsigned)phi << 32) | (unsigned)plo;
  return ok > k ? ok : k;
}

__global__ __attribute__((amdgpu_flat_work_group_size(THREADS_, THREADS_),
                          amdgpu_waves_per_eu(4, 4)))
void fps_kernel(const float* __restrict__ x, float* __restrict__ out,
                unsigned long long* __restrict__ wkeys,
                unsigned* __restrict__ wtags)
{
#pragma clang fp contract(off)
  const int bid  = blockIdx.x;
  const int b    = bid & 15;      // cloud id (bid = r*16 + b -> same XCD pair)
  const int r    = bid >> 4;      // sub-block 0/1
  const int t    = threadIdx.x;
  const int lane = t & 63;
  const int wave = t >> 6;

  // x,y of this block's 8192 points; array oversized to 88KB so LDS-implied
  // occupancy is 1 block/CU (only first PPB_ entries used).
  __shared__ float2 s_xy[XYPAD_];
  // parity-double-buffered per-wave argmax keys: one barrier per iteration
  __shared__ unsigned long long s_key[2][NW_];

  const float* xb  = x + (size_t)b * (N_ * 3);
  float* out_x     = out;                        // [B*K*3] f32 (bf16-grid values)
  float* out_batch = out + (size_t)B_ * K_ * 3;  // [B*K]   f32 cloud ids

  // batch output (both blocks write the same values; benign overlap)
  {
    const float bb = (float)b;
    for (int i = t; i < K_; i += THREADS_) out_batch[b * K_ + i] = bb;
  }

  // z and running-min in named registers; x,y staged to LDS.
  // Slot i of thread t = cloud-global point r*8192 + i*1024 + t.
#define DECLP(i) float pz##i, m##i;
  PTS_LIST(DECLP)
#undef DECLP

#define LOADP(i) { const float* p_ = xb + 3 * (r * PPB_ + (i) * THREADS_ + t); \
                   float2 v_; v_.x = p_[0]; v_.y = p_[1];                      \
                   s_xy[(i) * THREADS_ + t] = v_;                              \
                   pz##i = p_[2]; m##i = __builtin_inff(); }
  PTS_LIST(LOADP)
#undef LOADP

  // dist update (bit-exact FMA-V1), min into m##i; x,y from LDS (same bits)
#define UPD(i) { const float2 v_ = s_xy[(i) * THREADS_ + t];                    \
                 const float dx_ = v_.x - cx;                                   \
                 const float dy_ = v_.y - cy;                                   \
                 const float dz_ = pz##i - cz;                                  \
                 const float d_  = __builtin_fmaf(dz_, dz_,                     \
                                   __builtin_fmaf(dx_, dx_, dy_ * dy_));        \
                 m##i = fminf(m##i, d_); }

  // max3 tree over the 8 m values; value identical to sequential max.
#define MAXTREE(M_) { const float t0_ = fmaxf(fmaxf(m0, m1), m2);    \
                      const float t1_ = fmaxf(fmaxf(m3, m4), m5);    \
                      M_ = fmaxf(fmaxf(t0_, t1_), fmaxf(m6, m7)); }

  // descending equality chain: final bs = smallest slot with m==M
#define IDXCHAIN(M_, BS_) { BS_ = 7;                                 \
      if (m6 == M_) BS_ = 6; if (m5 == M_) BS_ = 5;                  \
      if (m4 == M_) BS_ = 4; if (m3 == M_) BS_ = 3;                  \
      if (m2 == M_) BS_ = 2; if (m1 == M_) BS_ = 1;                  \
      if (m0 == M_) BS_ = 0; }

  // per-thread argmax -> wave argmax -> per-wave key in LDS
#define REDUCE_AND_POST(PARITY) {                                        \
      float bv; int bs;                                                  \
      MAXTREE(bv)                                                        \
      IDXCHAIN(bv, bs)                                                   \
      const unsigned bg = (unsigned)(r * PPB_ + bs * THREADS_ + t);      \
      float wv; unsigned wg;                                             \
      wave_argmax(bv, bg, wv, wg);                                       \
      if (lane == 0) {                                                   \
        union { float f; unsigned u; } cv; cv.f = wv;                    \
        s_key[PARITY][wave] =                                            \
            ((unsigned long long)cv.u << 32) | (unsigned)~wg;            \
      } }

  // ---- iteration 0: seed = point 0 (known to both blocks) ----
  float cx = xb[0], cy = xb[1], cz = xb[2];
  if (r == 0 && t == 0) {
    const uint64_t o = ((uint64_t)b * K_) * 3;
    out_x[o + 0] = bfr(cx); out_x[o + 1] = bfr(cy); out_x[o + 2] = bfr(cz);
  }

  PTS_LIST(UPD)                      // m_i = d_i (min with +inf)
  REDUCE_AND_POST(0)
  __syncthreads();

  // ---- iterations 1..K-1 ----
  for (int j = 1; j < K_; ++j) {
    const int rp = (j - 1) & 1;      // intra-block key parity to read
    const int wp = j & 1;            // intra-block key parity to write
    const int gp = j & 1;            // global exchange slot parity

    // intra-block finalize: 16 per-wave keys broadcast (lane&15), 4 DPP
    // levels within each 16-lane row -> every lane holds the block key.
    unsigned long long bk = s_key[rp][lane & 15];
    bk = kmax_dpp<0xB1>(bk);   // quad_perm lane^1
    bk = kmax_dpp<0x4E>(bk);   // quad_perm lane^2
    bk = kmax_dpp<0x141>(bk);  // row_half_mirror (lane^7, covers ^4)
    bk = kmax_dpp<0x140>(bk);  // row_mirror (lane^15, covers ^8)

    // publish this block's key (once per iteration)
    const int widx = ((b << 1) | gp) * G_ + r;
    const int ridx = ((b << 1) | gp) * G_ + (1 - r);
    if (t == 0) {
      __hip_atomic_store(&wkeys[widx], bk, __ATOMIC_RELAXED,
                         __HIP_MEMORY_SCOPE_AGENT);
      __hip_atomic_store(&wtags[widx], (unsigned)j, __ATOMIC_RELEASE,
                         __HIP_MEMORY_SCOPE_AGENT);
    }

    // poll remote tag: RELAXED loads (L1-bypassing, no invalidate storm);
    // one acquire fence after match, then relaxed key load.
    unsigned tg;
    do {
      tg = __hip_atomic_load(&wtags[ridx], __ATOMIC_RELAXED,
                             __HIP_MEMORY_SCOPE_AGENT);
    } while (tg != (unsigned)j);
    __builtin_amdgcn_fence(__ATOMIC_ACQUIRE, "agent");
    const unsigned long long rk =
        __hip_atomic_load(&wkeys[ridx], __ATOMIC_RELAXED,
                          __HIP_MEMORY_SCOPE_AGENT);

    const unsigned long long ck = rk > bk ? rk : bk;   // cloud-wide winner
    const unsigned idx = ~(unsigned)ck;                // global point index
    const int gu = __builtin_amdgcn_readfirstlane((int)idx);

    // center: winner may be in the other block -> uniform scalar loads from
    // xb (cloud data is L2-resident; ~200cy, partially hidden under UPD)
    cx = xb[3 * gu + 0];
    cy = xb[3 * gu + 1];
    cz = xb[3 * gu + 2];
    if (r == 0 && t == 0) {
      const uint64_t o = ((uint64_t)b * K_ + j) * 3;
      out_x[o + 0] = bfr(cx); out_x[o + 1] = bfr(cy); out_x[o + 2] = bfr(cz);
    }

    // update mind + per-thread/wave argmax for next round
    PTS_LIST(UPD)
    REDUCE_AND_POST(wp)
    __syncthreads();
  }
#undef UPD
#undef MAXTREE
#undef IDXCHAIN
#undef REDUCE_AND_POST

}

extern "C" void kernel_launch(void* const* d_in, const int* in_sizes, int n_in,
                              void* d_out, int out_size, void* d_ws, size_t ws_size,
                              hipStream_t stream) {
  const float* x = (const float*)d_in[0];  // f32, [B*N, 3]
  float* out     = (float*)d_out;          // f32: [B*K*3] coords + [B*K] batch
  (void)in_sizes; (void)n_in; (void)out_size; (void)ws_size;

  unsigned long long* wkeys = (unsigned long long*)d_ws;   // [16][2][2] u64
  unsigned* wtags = (unsigned*)((char*)d_ws +
                    (size_t)B_ * 2 * G_ * sizeof(unsigned long long));
  const size_t sync_bytes = (size_t)B_ * 2 * G_ *
      (sizeof(unsigned long long) + sizeof(unsigned));     // 768 B

  // zero tags/keys every call (stream-ordered; graph-capturable)
  hipMemsetAsync(d_ws, 0, sync_bytes, stream);
  hipLaunchKernelGGL(fps_kernel, dim3(B_ * G_), dim3(THREADS_), 0, stream,
                     x, out, wkeys, wtags);
}

// Round 16
// 5478.453 us; speedup vs baseline: 3.9181x; 3.9181x over previous
//
#include <hip/hip_runtime.h>
#include <cstdint>

// Reference semantics (validated, absmax=0.0 — DO NOT change arithmetic):
//  - selection on RAW f32 coords, distance = fma(dz,dz, fma(dx,dx, dy*dy))
//    with dx/dy/dz plain f32 subs;
//  - min/argmax exact, FIRST-index tie-break (min global point index);
//  - output coords bf16-RNE-rounded, batch = float b.
//
// R27 = R19 restored verbatim (best: 5417-5461us). Search summary:
//  - Cross-block sync per iteration is intrinsically us-scale (R14: 19us/iter
//    acquire-poll; R26: ~4us/iter relaxed-poll+fence) vs the 1.32us/iter
//    total budget -> single CU per cloud is a hard constraint (16/256 CUs).
//  - Against R19, every internal lever regressed or nulled: VALU-count cut
//    (R23), DS-count cut (R25), tail cut (R24), 512thr residency (R22),
//    packed f32 (R20). R19 is a serial-dependency-bound local optimum:
//    ~3174 cyc/iter, active-CU VALU ~100% busy.
// Structure: x,y in LDS (float2 s_xy[16384], 128KB, 1 block/CU; per-iter
// reads are immediate-offset ds_read_b64 on the DS pipe), z,m in 32 named
// regs, DPP prefix+bcast wave argmax, u64-key DPP block finalize, parity
// double-buffer, one barrier/iter, center = LDS xy + global z.
#pragma clang fp contract(off)

#define B_ 16
#define N_ 16384
#define K_ 4096
#define THREADS_ 1024
#define PTS_ (N_ / THREADS_)   // 16 points per thread
#define NW_ (THREADS_ / 64)    // 16 waves per block

#define PTS_LIST(X) \
  X(0) X(1) X(2) X(3) X(4) X(5) X(6) X(7) \
  X(8) X(9) X(10) X(11) X(12) X(13) X(14) X(15)

// f32 -> bf16 RNE, returned as the bf16-representable f32 (finite inputs)
__device__ __forceinline__ float bfr(float f) {
  union { float f; uint32_t i; } c; c.f = f;
  c.i = (c.i + 0x7FFFu + ((c.i >> 16) & 1u)) & 0xFFFF0000u;
  return c.f;
}

// ---- DPP helpers (ctrl must be compile-time constant -> template) ----------
// fmax with a DPP-permuted copy; invalid-source lanes contribute 0
// (identity: all reduced values are >= 0).
template <int CTRL>
__device__ __forceinline__ float dpp_fmax(float v) {
  union { float f; int i; } s, p;
  s.f = v;
  p.i = __builtin_amdgcn_update_dpp(0, s.i, CTRL, 0xF, 0xF, false);
  return fmaxf(v, p.f);
}
// u32 min with a DPP-permuted copy; invalid-source lanes contribute ~0u.
template <int CTRL>
__device__ __forceinline__ unsigned dpp_umin(unsigned v) {
  const int p = __builtin_amdgcn_update_dpp((int)0xFFFFFFFFu, (int)v,
                                            CTRL, 0xF, 0xF, false);
  const unsigned pu = (unsigned)p;
  return pu < v ? pu : v;
}

// wave-wide (max bv, min bg among maxed) -> (wv, wg), uniform in all lanes.
// Classic GCN 6-step: row_shr 1/2/4/8 (prefix within rows of 16) then
// row_bcast:15, row_bcast:31 -> lane 63 holds the full-wave result.
__device__ __forceinline__ void wave_argmax(float bv, unsigned bg,
                                            float& wv, unsigned& wg) {
  float v = bv;
  v = dpp_fmax<0x111>(v);  // row_shr:1
  v = dpp_fmax<0x112>(v);  // row_shr:2
  v = dpp_fmax<0x114>(v);  // row_shr:4
  v = dpp_fmax<0x118>(v);  // row_shr:8
  v = dpp_fmax<0x142>(v);  // row_bcast:15
  v = dpp_fmax<0x143>(v);  // row_bcast:31
  union { float f; int i; } mx;
  mx.i = __builtin_amdgcn_readlane(__builtin_bit_cast(int, v), 63);
  unsigned c = (bv == mx.f) ? bg : 0xFFFFFFFFu;
  c = dpp_umin<0x111>(c);
  c = dpp_umin<0x112>(c);
  c = dpp_umin<0x114>(c);
  c = dpp_umin<0x118>(c);
  c = dpp_umin<0x142>(c);
  c = dpp_umin<0x143>(c);
  wg = (unsigned)__builtin_amdgcn_readlane((int)c, 63);
  wv = mx.f;
}

// u64 key max over a DPP lane-permutation (block-finalize butterfly; key is
// (f32bits(dist)<<32)|~idx so u64 max == (max dist, min index)). Exact.
template <int CTRL>
__device__ __forceinline__ unsigned long long kmax_dpp(unsigned long long k) {
  const int lo = (int)(unsigned)k;
  const int hi = (int)(unsigned)(k >> 32);
  const int plo = __builtin_amdgcn_update_dpp(lo, lo, CTRL, 0xF, 0xF, true);
  const int phi = __builtin_amdgcn_update_dpp(hi, hi, CTRL, 0xF, 0xF, true);
  const unsigned long long ok =
      ((unsigned long long)(unsigned)phi << 32) | (unsigned)plo;
  return ok > k ? ok : k;
}

__global__ __attribute__((amdgpu_flat_work_group_size(THREADS_, THREADS_),
                          amdgpu_waves_per_eu(4, 4)))
void fps_kernel(const float* __restrict__ x, float* __restrict__ out)
{
#pragma clang fp contract(off)
  const int b    = blockIdx.x;
  const int t    = threadIdx.x;
  const int lane = t & 63;
  const int wave = t >> 6;

  // x,y of all 16384 points (128 KB). Thread t reads only slots {i*1024+t}
  // in the update loop (immediate-offset ds_read_b64); center reads are
  // uniform-address broadcasts. Written once at init.
  __shared__ float2 s_xy[N_];
  // parity-double-buffered per-wave argmax keys: one barrier per iteration
  __shared__ unsigned long long s_key[2][NW_];

  const float* xb  = x + (size_t)b * (N_ * 3);
  float* out_x     = out;                        // [B*K*3] f32 (bf16-grid values)
  float* out_batch = out + (size_t)B_ * K_ * 3;  // [B*K]   f32 cloud ids

  // batch output (buffer re-poisoned every call -> rewrite every call)
  {
    const float bb = (float)b;
    for (int i = t; i < K_; i += THREADS_) out_batch[b * K_ + i] = bb;
  }

  // z and running-min in named registers; x,y staged to LDS
#define DECLP(i) float pz##i, m##i;
  PTS_LIST(DECLP)
#undef DECLP

#define LOADP(i) { const float* p_ = xb + 3 * ((i) * THREADS_ + t); \
                   float2 v_; v_.x = p_[0]; v_.y = p_[1];           \
                   s_xy[(i) * THREADS_ + t] = v_;                   \
                   pz##i = p_[2]; m##i = __builtin_inff(); }
  PTS_LIST(LOADP)
#undef LOADP

  // dist update (bit-exact FMA-V1), min into m##i; x,y from LDS (same bits)
#define UPD(i) { const float2 v_ = s_xy[(i) * THREADS_ + t];                    \
                 const float dx_ = v_.x - cx;                                   \
                 const float dy_ = v_.y - cy;                                   \
                 const float dz_ = pz##i - cz;                                  \
                 const float d_  = __builtin_fmaf(dz_, dz_,                     \
                                   __builtin_fmaf(dx_, dx_, dy_ * dy_));        \
                 m##i = fminf(m##i, d_); }

  // max3 tree over the 16 m values (fmaxf nests fuse to v_max3_f32); value
  // identical to the sequential scan's max (same finite set).
#define MAXTREE(M_) { const float t0_ = fmaxf(fmaxf(m0,  m1),  m2);  \
                      const float t1_ = fmaxf(fmaxf(m3,  m4),  m5);  \
                      const float t2_ = fmaxf(fmaxf(m6,  m7),  m8);  \
                      const float t3_ = fmaxf(fmaxf(m9,  m10), m11); \
                      const float t4_ = fmaxf(fmaxf(m12, m13), m14); \
                      const float u0_ = fmaxf(fmaxf(t0_, t1_), t2_); \
                      const float u1_ = fmaxf(fmaxf(t3_, t4_), m15); \
                      M_ = fmaxf(u0_, u1_); }

  // descending equality chain: final bs = smallest slot with m==M
#define IDXCHAIN(M_, BS_) { BS_ = 15;                                \
      if (m14 == M_) BS_ = 14; if (m13 == M_) BS_ = 13;              \
      if (m12 == M_) BS_ = 12; if (m11 == M_) BS_ = 11;              \
      if (m10 == M_) BS_ = 10; if (m9  == M_) BS_ = 9;               \
      if (m8  == M_) BS_ = 8;  if (m7  == M_) BS_ = 7;               \
      if (m6  == M_) BS_ = 6;  if (m5  == M_) BS_ = 5;               \
      if (m4  == M_) BS_ = 4;  if (m3  == M_) BS_ = 3;               \
      if (m2  == M_) BS_ = 2;  if (m1  == M_) BS_ = 1;               \
      if (m0  == M_) BS_ = 0; }

  // per-thread argmax -> wave argmax -> per-wave key in LDS
#define REDUCE_AND_POST(PARITY) {                                        \
      float bv; int bs;                                                  \
      MAXTREE(bv)                                                        \
      IDXCHAIN(bv, bs)                                                   \
      const unsigned bg = (unsigned)(bs * THREADS_ + t);                 \
      float wv; unsigned wg;                                             \
      wave_argmax(bv, bg, wv, wg);                                       \
      if (lane == 0) {                                                   \
        union { float f; unsigned u; } cv; cv.f = wv;                    \
        s_key[PARITY][wave] =                                            \
            ((unsigned long long)cv.u << 32) | (unsigned)~wg;            \
      } }

  // ---- iteration 0: seed = point 0 ----
  float cx = xb[0], cy = xb[1], cz = xb[2];
  if (t == 0) {
    const uint64_t o = ((uint64_t)b * K_) * 3;
    out_x[o + 0] = bfr(cx); out_x[o + 1] = bfr(cy); out_x[o + 2] = bfr(cz);
  }

  PTS_LIST(UPD)                      // m_i = d_i (min with +inf)
  REDUCE_AND_POST(0)
  __syncthreads();

  // ---- iterations 1..K-1 ----
  for (int j = 1; j < K_; ++j) {
    const int rp = (j - 1) & 1;
    const int wp = j & 1;

    // finalize block argmax: 16 per-wave keys broadcast (lane&15), 4 DPP
    // levels within each 16-lane row -> every lane holds the block winner.
    unsigned long long k = s_key[rp][lane & 15];
    k = kmax_dpp<0xB1>(k);    // quad_perm lane^1
    k = kmax_dpp<0x4E>(k);    // quad_perm lane^2
    k = kmax_dpp<0x141>(k);   // row_half_mirror (lane^7, covers ^4)
    k = kmax_dpp<0x140>(k);   // row_mirror (lane^15, covers ^8)
    const unsigned idx = ~(unsigned)k;           // winner global point index
    const int gu = __builtin_amdgcn_readfirstlane((int)idx);

    // center: x,y from LDS (uniform broadcast read), z from global (its
    // ~200cy L2 latency hides under the cz-independent dx/dy VALU below)
    const float2 cxy = s_xy[gu];
    cx = cxy.x; cy = cxy.y;
    cz = xb[3 * gu + 2];
    if (t == 0) {
      const uint64_t o = ((uint64_t)b * K_ + j) * 3;
      out_x[o + 0] = bfr(cx); out_x[o + 1] = bfr(cy); out_x[o + 2] = bfr(cz);
    }

    // update mind + per-thread/wave argmax for next round
    PTS_LIST(UPD)
    REDUCE_AND_POST(wp)
    __syncthreads();
  }
#undef UPD
#undef MAXTREE
#undef IDXCHAIN
#undef REDUCE_AND_POST

}

extern "C" void kernel_launch(void* const* d_in, const int* in_sizes, int n_in,
                              void* d_out, int out_size, void* d_ws, size_t ws_size,
                              hipStream_t stream) {
  const float* x = (const float*)d_in[0];  // f32, [B*N, 3]
  float* out     = (float*)d_out;          // f32: [B*K*3] coords + [B*K] batch
  (void)in_sizes; (void)n_in; (void)out_size; (void)d_ws; (void)ws_size;
  hipLaunchKernelGGL(fps_kernel, dim3(B_), dim3(THREADS_), 0, stream, x, out);
}